// Round 4
// baseline (300.730 us; speedup 1.0000x reference)
//
#include <hip/hip_runtime.h>
#include <hip/hip_bf16.h>
#include <float.h>

#define LEAKY 0.2f
#define SCAN_B 512

// ---------------- CSR build ----------------
__global__ void deg_k(const int* __restrict__ dst, int* __restrict__ deg, int E) {
    int e = blockIdx.x * blockDim.x + threadIdx.x;
    if (e < E) atomicAdd(&deg[dst[e]], 1);
}

__global__ void scan1_k(const int* __restrict__ deg, int* __restrict__ offs,
                        int* __restrict__ bsum, int N) {
    __shared__ int s[SCAN_B];
    int i = blockIdx.x * SCAN_B + threadIdx.x;
    int v = (i < N) ? deg[i] : 0;
    s[threadIdx.x] = v;
    __syncthreads();
    for (int off = 1; off < SCAN_B; off <<= 1) {
        int t = (threadIdx.x >= off) ? s[threadIdx.x - off] : 0;
        __syncthreads();
        s[threadIdx.x] += t;
        __syncthreads();
    }
    if (i < N) offs[i] = s[threadIdx.x] - v;   // exclusive
    if (threadIdx.x == SCAN_B - 1) bsum[blockIdx.x] = s[threadIdx.x];
}

__global__ void scan2_k(int* __restrict__ bsum, int NB) {
    if (blockIdx.x == 0 && threadIdx.x == 0) {
        int run = 0;
        for (int b = 0; b < NB; b++) { int t = bsum[b]; bsum[b] = run; run += t; }
    }
}

__global__ void scan3_k(int* __restrict__ offs, const int* __restrict__ bsum, int N) {
    int i = blockIdx.x * blockDim.x + threadIdx.x;
    if (i < N) offs[i] += bsum[i / SCAN_B];
}

// packed scatter: one 4B store per edge; atomicAdd on offs itself.
// post-scatter: offs[n] == original offs[n+1]  (range of n = [n? offs[n-1]:0, offs[n]))
__global__ void scatter_k(const int* __restrict__ src, const int* __restrict__ dst,
                          const int* __restrict__ et, int* __restrict__ offs,
                          unsigned* __restrict__ pedge, int E) {
    int e = blockIdx.x * blockDim.x + threadIdx.x;
    if (e < E) {
        int d = dst[e];
        int j = atomicAdd(&offs[d], 1);
        pedge[j] = ((unsigned)et[e] << 28) | (unsigned)src[e];
    }
}

// ---------------- fused GEMM + logits (H = 64 baked in) ----------------
template <int FIN>
__global__ __launch_bounds__(256) void gemm_fused_k(const float* __restrict__ in,
                                                    const float* __restrict__ W,
                                                    const float* __restrict__ a_s,
                                                    const float* __restrict__ a_d,
                                                    float* __restrict__ h,
                                                    float* __restrict__ ls,
                                                    float* __restrict__ ld_, int N) {
    __shared__ float in_s[64][FIN + 4];
    __shared__ float Wl[FIN][64];

    const int rbase = blockIdx.x * 64;
    const int NV4 = FIN / 4;

    for (int t = threadIdx.x; t < FIN * 16; t += 256) {
        float4 v = *(const float4*)(W + (size_t)t * 4);
        *(float4*)((float*)Wl + (size_t)t * 4) = v;
    }
    for (int t = threadIdx.x; t < 64 * NV4; t += 256) {
        int r = t / NV4, k4 = t % NV4;
        int gr = rbase + r;
        if (gr >= N) gr = N - 1;
        float4 v = *(const float4*)(in + (size_t)gr * FIN + k4 * 4);
        *(float4*)&in_s[r][k4 * 4] = v;
    }
    __syncthreads();

    const int ty = threadIdx.x >> 4;
    const int tx = threadIdx.x & 15;

    float acc[4][4] = {};
#pragma unroll 4
    for (int k = 0; k < FIN; ++k) {
        float4 wv = *(const float4*)&Wl[k][tx * 4];
        float a0 = in_s[ty * 4 + 0][k];
        float a1 = in_s[ty * 4 + 1][k];
        float a2 = in_s[ty * 4 + 2][k];
        float a3 = in_s[ty * 4 + 3][k];
        acc[0][0] += a0 * wv.x; acc[0][1] += a0 * wv.y; acc[0][2] += a0 * wv.z; acc[0][3] += a0 * wv.w;
        acc[1][0] += a1 * wv.x; acc[1][1] += a1 * wv.y; acc[1][2] += a1 * wv.z; acc[1][3] += a1 * wv.w;
        acc[2][0] += a2 * wv.x; acc[2][1] += a2 * wv.y; acc[2][2] += a2 * wv.z; acc[2][3] += a2 * wv.w;
        acc[3][0] += a3 * wv.x; acc[3][1] += a3 * wv.y; acc[3][2] += a3 * wv.z; acc[3][3] += a3 * wv.w;
    }

    float4 asv = *(const float4*)(a_s + tx * 4);
    float4 adv = *(const float4*)(a_d + tx * 4);
#pragma unroll
    for (int i = 0; i < 4; ++i) {
        int row = rbase + ty * 4 + i;
        float lsv = acc[i][0] * asv.x + acc[i][1] * asv.y + acc[i][2] * asv.z + acc[i][3] * asv.w;
        float ldv = acc[i][0] * adv.x + acc[i][1] * adv.y + acc[i][2] * adv.z + acc[i][3] * adv.w;
        for (int o = 1; o < 16; o <<= 1) {
            lsv += __shfl_xor(lsv, o, 64);
            ldv += __shfl_xor(ldv, o, 64);
        }
        if (row < N) {
            float4 hv = make_float4(acc[i][0], acc[i][1], acc[i][2], acc[i][3]);
            *(float4*)&h[(size_t)row * 64 + tx * 4] = hv;
            if (tx == 0) { ls[row] = lsv; ld_[row] = ldv; }
        }
    }
}

// ---------------- edge softmax: one node per 16-lane group ----------------
__global__ __launch_bounds__(256) void softmax_k(const int* __restrict__ offs,
                                                 const unsigned* __restrict__ pedge,
                                                 const float* __restrict__ ls,
                                                 const float* __restrict__ ld_,
                                                 const float* __restrict__ etb,
                                                 float* __restrict__ ew,
                                                 float* __restrict__ denom, int N) {
    int grp = threadIdx.x >> 4;
    int l = threadIdx.x & 15;
    int n = blockIdx.x * 16 + grp;
    if (n >= N) return;
    int s0 = n ? offs[n - 1] : 0;
    int s1 = offs[n];
    float myld = ld_[n];
    float mx = -FLT_MAX;
    for (int j = s0 + l; j < s1; j += 16) {
        unsigned p = pedge[j];
        float ev = ls[p & 0x0FFFFFFFu] + myld + etb[p >> 28];
        ev = ev > 0.f ? ev : LEAKY * ev;
        ew[j] = ev;
        mx = fmaxf(mx, ev);
    }
#pragma unroll
    for (int o = 1; o < 16; o <<= 1) mx = fmaxf(mx, __shfl_xor(mx, o, 64));
    float s = 0.f;
    for (int j = s0 + l; j < s1; j += 16) {
        float w = __expf(ew[j] - mx);
        ew[j] = w;
        s += w;
    }
#pragma unroll
    for (int o = 1; o < 16; o <<= 1) s += __shfl_xor(s, o, 64);
    if (l == 0) denom[n] = s;
}

// ---------------- weighted gather: 16 lanes x float4 per node, unroll 4 ----------------
__global__ __launch_bounds__(256) void gather_k(const int* __restrict__ offs,
                                                const unsigned* __restrict__ pedge,
                                                const float* __restrict__ ew,
                                                const float* __restrict__ denom,
                                                const float* __restrict__ h,
                                                float* __restrict__ out, int N) {
    int grp = threadIdx.x >> 4;
    int l = threadIdx.x & 15;
    int n = blockIdx.x * 16 + grp;
    if (n >= N) return;
    int s0 = n ? offs[n - 1] : 0;
    int s1 = offs[n];
    const float4* h4 = (const float4*)h;
    float ax = 0.f, ay = 0.f, az = 0.f, aw = 0.f;
    int j = s0;
    for (; j + 3 < s1; j += 4) {
        unsigned p0 = pedge[j], p1 = pedge[j + 1], p2 = pedge[j + 2], p3 = pedge[j + 3];
        float w0 = ew[j], w1 = ew[j + 1], w2 = ew[j + 2], w3 = ew[j + 3];
        float4 v0 = h4[(size_t)(p0 & 0x0FFFFFFFu) * 16 + l];
        float4 v1 = h4[(size_t)(p1 & 0x0FFFFFFFu) * 16 + l];
        float4 v2 = h4[(size_t)(p2 & 0x0FFFFFFFu) * 16 + l];
        float4 v3 = h4[(size_t)(p3 & 0x0FFFFFFFu) * 16 + l];
        ax += v0.x * w0 + v1.x * w1 + v2.x * w2 + v3.x * w3;
        ay += v0.y * w0 + v1.y * w1 + v2.y * w2 + v3.y * w3;
        az += v0.z * w0 + v1.z * w1 + v2.z * w2 + v3.z * w3;
        aw += v0.w * w0 + v1.w * w1 + v2.w * w2 + v3.w * w3;
    }
    for (; j < s1; j++) {
        unsigned p0 = pedge[j];
        float w0 = ew[j];
        float4 v0 = h4[(size_t)(p0 & 0x0FFFFFFFu) * 16 + l];
        ax += v0.x * w0; ay += v0.y * w0; az += v0.z * w0; aw += v0.w * w0;
    }
    float invd = 1.0f / (denom[n] + 1e-16f);
    float4 r;
    r.x = fmaxf(ax * invd, 0.f);
    r.y = fmaxf(ay * invd, 0.f);
    r.z = fmaxf(az * invd, 0.f);
    r.w = fmaxf(aw * invd, 0.f);
    ((float4*)out)[(size_t)n * 16 + l] = r;
}

// ---------------- pooling + critic MLP ----------------
__global__ __launch_bounds__(256) void pool_k(const int* __restrict__ batch,
                                              const float* __restrict__ act,
                                              float* __restrict__ gp, int N) {
    __shared__ float s[256];
    int g = blockIdx.x;
    int f = threadIdx.x & 63;
    int rc = threadIdx.x >> 6;
    int lo, hi;
    { int a = 0, b = N; while (a < b) { int m = (a + b) >> 1; if (batch[m] < g) a = m + 1; else b = m; } lo = a; }
    { int a = lo, b = N; while (a < b) { int m = (a + b) >> 1; if (batch[m] < g + 1) a = m + 1; else b = m; } hi = a; }
    float acc = 0.f;
    for (int n = lo + rc; n < hi; n += 4) acc += act[(size_t)n * 64 + f];
    s[threadIdx.x] = acc;
    __syncthreads();
    if (threadIdx.x < 64)
        gp[g * 64 + threadIdx.x] = s[threadIdx.x] + s[threadIdx.x + 64] + s[threadIdx.x + 128] + s[threadIdx.x + 192];
}

__global__ __launch_bounds__(128) void mlp_k(const float* __restrict__ gp,
                                             const float* __restrict__ W0,
                                             const float* __restrict__ b0,
                                             const float* __restrict__ W1,
                                             const float* __restrict__ b1,
                                             const float* __restrict__ fW,
                                             const float* __restrict__ fb,
                                             float* __restrict__ out) {
    __shared__ float gv[64];
    __shared__ float t1[128];
    __shared__ float t2[128];
    __shared__ float part[2];
    int g = blockIdx.x;
    int t = threadIdx.x;
    if (t < 64) gv[t] = gp[g * 64 + t];
    __syncthreads();
    float acc = b0[t];
    for (int k = 0; k < 64; k++) acc += gv[k] * W0[k * 128 + t];
    t1[t] = fmaxf(acc, 0.f);
    __syncthreads();
    acc = b1[t];
    for (int k = 0; k < 128; k++) acc += t1[k] * W1[k * 128 + t];
    t2[t] = fmaxf(acc, 0.f);
    __syncthreads();
    float v = t2[t] * fW[t];
    for (int o = 32; o > 0; o >>= 1) v += __shfl_xor(v, o, 64);
    if ((t & 63) == 0) part[t >> 6] = v;
    __syncthreads();
    if (t == 0) out[g] = part[0] + part[1] + fb[0];
}

extern "C" void kernel_launch(void* const* d_in, const int* in_sizes, int n_in,
                              void* d_out, int out_size, void* d_ws, size_t ws_size,
                              hipStream_t stream) {
    const float* x    = (const float*)d_in[0];
    const int*   src  = (const int*)d_in[1];
    const int*   dst  = (const int*)d_in[2];
    const int*   et   = (const int*)d_in[3];
    const int*   batch= (const int*)d_in[4];
    const float* W0   = (const float*)d_in[6];
    const float* W1   = (const float*)d_in[7];
    const float* W2   = (const float*)d_in[8];
    const float* a_src= (const float*)d_in[9];
    const float* a_dst= (const float*)d_in[10];
    const float* etb  = (const float*)d_in[11];
    const float* eW0  = (const float*)d_in[12];
    const float* eb0  = (const float*)d_in[13];
    const float* eW1  = (const float*)d_in[14];
    const float* eb1  = (const float*)d_in[15];
    const float* fW   = (const float*)d_in[16];
    const float* fb   = (const float*)d_in[17];
    float* out = (float*)d_out;

    const int H = in_sizes[9] / 3;       // 64
    const int F = in_sizes[6] / H;       // 128
    const int N = in_sizes[0] / F;       // 50000
    const int E = in_sizes[1];           // 800000
    const int T = in_sizes[11] / 3;      // 3
    const int G = out_size;              // 512

    float*    hA    = (float*)d_ws;
    float*    hB    = hA + (size_t)N * 64;
    float*    ls    = hB + (size_t)N * 64;
    float*    ld_   = ls + N;
    float*    denom = ld_ + N;
    float*    ew    = denom + N;
    int*      deg   = (int*)(ew + E);
    int*      offs  = deg + N;
    unsigned* pedge = (unsigned*)(offs + N + 1);
    int*      bsum  = (int*)(pedge + E);

    const int NB = (N + SCAN_B - 1) / SCAN_B;

    hipMemsetAsync(deg, 0, (size_t)N * sizeof(int), stream);

    deg_k<<<(E + 255) / 256, 256, 0, stream>>>(dst, deg, E);
    scan1_k<<<NB, SCAN_B, 0, stream>>>(deg, offs, bsum, N);
    scan2_k<<<1, 1, 0, stream>>>(bsum, NB);
    scan3_k<<<NB, SCAN_B, 0, stream>>>(offs, bsum, N);
    scatter_k<<<(E + 255) / 256, 256, 0, stream>>>(src, dst, et, offs, pedge, E);

    const int NB64 = (N + 63) / 64;
    const int NB16 = (N + 15) / 16;

    // ---- layer 0 ----
    gemm_fused_k<128><<<NB64, 256, 0, stream>>>(x, W0, a_src + 0 * H, a_dst + 0 * H, hA, ls, ld_, N);
    softmax_k<<<NB16, 256, 0, stream>>>(offs, pedge, ls, ld_, etb + 0 * T, ew, denom, N);
    gather_k<<<NB16, 256, 0, stream>>>(offs, pedge, ew, denom, hA, hB, N);

    // ---- layer 1 ----
    gemm_fused_k<64><<<NB64, 256, 0, stream>>>(hB, W1, a_src + 1 * H, a_dst + 1 * H, hA, ls, ld_, N);
    softmax_k<<<NB16, 256, 0, stream>>>(offs, pedge, ls, ld_, etb + 1 * T, ew, denom, N);
    gather_k<<<NB16, 256, 0, stream>>>(offs, pedge, ew, denom, hA, hB, N);

    // ---- layer 2 ----
    gemm_fused_k<64><<<NB64, 256, 0, stream>>>(hB, W2, a_src + 2 * H, a_dst + 2 * H, hA, ls, ld_, N);
    softmax_k<<<NB16, 256, 0, stream>>>(offs, pedge, ls, ld_, etb + 2 * T, ew, denom, N);
    gather_k<<<NB16, 256, 0, stream>>>(offs, pedge, ew, denom, hA, hB, N);

    // ---- pool + MLP ----
    float* gp = ew;
    pool_k<<<G, 256, 0, stream>>>(batch, hB, gp, N);
    mlp_k<<<G, 128, 0, stream>>>(gp, eW0, eb0, eW1, eb1, fW, fb, out);
}

// Round 5
// 245.187 us; speedup vs baseline: 1.2265x; 1.2265x over previous
//
#include <hip/hip_runtime.h>
#include <hip/hip_bf16.h>
#include <float.h>

#define LEAKY 0.2f
#define SCAN_B 512

// ---------------- CSR build ----------------
// rank pass: deg histogram AND per-edge rank (coalesced store)
__global__ void rank_k(const int* __restrict__ dst, int* __restrict__ deg,
                       int* __restrict__ rank, int E) {
    int e = blockIdx.x * blockDim.x + threadIdx.x;
    if (e < E) rank[e] = atomicAdd(&deg[dst[e]], 1);
}

__global__ void scan1_k(const int* __restrict__ deg, int* __restrict__ offs,
                        int* __restrict__ bsum, int N) {
    __shared__ int s[SCAN_B];
    int i = blockIdx.x * SCAN_B + threadIdx.x;
    int v = (i < N) ? deg[i] : 0;
    s[threadIdx.x] = v;
    __syncthreads();
    for (int off = 1; off < SCAN_B; off <<= 1) {
        int t = (threadIdx.x >= off) ? s[threadIdx.x - off] : 0;
        __syncthreads();
        s[threadIdx.x] += t;
        __syncthreads();
    }
    if (i < N) offs[i] = s[threadIdx.x] - v;   // exclusive
    if (threadIdx.x == SCAN_B - 1) bsum[blockIdx.x] = s[threadIdx.x];
}

__global__ void scan2_k(int* __restrict__ bsum, int* __restrict__ offs, int NB, int N) {
    if (blockIdx.x == 0 && threadIdx.x == 0) {
        int run = 0;
        for (int b = 0; b < NB; b++) { int t = bsum[b]; bsum[b] = run; run += t; }
        offs[N] = run;
    }
}

__global__ void scan3_k(int* __restrict__ offs, const int* __restrict__ bsum, int N) {
    int i = blockIdx.x * blockDim.x + threadIdx.x;
    if (i < N) offs[i] += bsum[i / SCAN_B];
}

// atomic-free scatter: position = offs[dst] + rank  (offs stays exclusive)
__global__ void scatter_k(const int* __restrict__ src, const int* __restrict__ dst,
                          const int* __restrict__ et, const int* __restrict__ offs,
                          const int* __restrict__ rank, unsigned* __restrict__ pedge, int E) {
    int e = blockIdx.x * blockDim.x + threadIdx.x;
    if (e < E) {
        int j = offs[dst[e]] + rank[e];
        pedge[j] = ((unsigned)et[e] << 28) | (unsigned)src[e];
    }
}

// ---------------- fused GEMM + logits (H = 64 baked in) ----------------
template <int FIN>
__global__ __launch_bounds__(256) void gemm_fused_k(const float* __restrict__ in,
                                                    const float* __restrict__ W,
                                                    const float* __restrict__ a_s,
                                                    const float* __restrict__ a_d,
                                                    float* __restrict__ h,
                                                    float* __restrict__ ls,
                                                    float* __restrict__ ld_, int N) {
    __shared__ float in_s[64][FIN + 4];
    __shared__ float Wl[FIN][64];

    const int rbase = blockIdx.x * 64;
    const int NV4 = FIN / 4;

    for (int t = threadIdx.x; t < FIN * 16; t += 256) {
        float4 v = *(const float4*)(W + (size_t)t * 4);
        *(float4*)((float*)Wl + (size_t)t * 4) = v;
    }
    for (int t = threadIdx.x; t < 64 * NV4; t += 256) {
        int r = t / NV4, k4 = t % NV4;
        int gr = rbase + r;
        if (gr >= N) gr = N - 1;
        float4 v = *(const float4*)(in + (size_t)gr * FIN + k4 * 4);
        *(float4*)&in_s[r][k4 * 4] = v;
    }
    __syncthreads();

    const int ty = threadIdx.x >> 4;
    const int tx = threadIdx.x & 15;

    float acc[4][4] = {};
#pragma unroll 4
    for (int k = 0; k < FIN; ++k) {
        float4 wv = *(const float4*)&Wl[k][tx * 4];
        float a0 = in_s[ty * 4 + 0][k];
        float a1 = in_s[ty * 4 + 1][k];
        float a2 = in_s[ty * 4 + 2][k];
        float a3 = in_s[ty * 4 + 3][k];
        acc[0][0] += a0 * wv.x; acc[0][1] += a0 * wv.y; acc[0][2] += a0 * wv.z; acc[0][3] += a0 * wv.w;
        acc[1][0] += a1 * wv.x; acc[1][1] += a1 * wv.y; acc[1][2] += a1 * wv.z; acc[1][3] += a1 * wv.w;
        acc[2][0] += a2 * wv.x; acc[2][1] += a2 * wv.y; acc[2][2] += a2 * wv.z; acc[2][3] += a2 * wv.w;
        acc[3][0] += a3 * wv.x; acc[3][1] += a3 * wv.y; acc[3][2] += a3 * wv.z; acc[3][3] += a3 * wv.w;
    }

    float4 asv = *(const float4*)(a_s + tx * 4);
    float4 adv = *(const float4*)(a_d + tx * 4);
#pragma unroll
    for (int i = 0; i < 4; ++i) {
        int row = rbase + ty * 4 + i;
        float lsv = acc[i][0] * asv.x + acc[i][1] * asv.y + acc[i][2] * asv.z + acc[i][3] * asv.w;
        float ldv = acc[i][0] * adv.x + acc[i][1] * adv.y + acc[i][2] * adv.z + acc[i][3] * adv.w;
        for (int o = 1; o < 16; o <<= 1) {
            lsv += __shfl_xor(lsv, o, 64);
            ldv += __shfl_xor(ldv, o, 64);
        }
        if (row < N) {
            float4 hv = make_float4(acc[i][0], acc[i][1], acc[i][2], acc[i][3]);
            *(float4*)&h[(size_t)row * 64 + tx * 4] = hv;
            if (tx == 0) { ls[row] = lsv; ld_[row] = ldv; }
        }
    }
}

// ---------------- fused edge softmax + weighted gather ----------------
// One node per 16-lane group. Loop1: lane-parallel max. Loop2: group-serial
// over edges; all 16 lanes redundantly compute w (broadcast loads, free in
// wave time), each lane accumulates its float4 slice of w*h[src].
__global__ __launch_bounds__(256) void attn_k(const int* __restrict__ offs,
                                              const unsigned* __restrict__ pedge,
                                              const float* __restrict__ ls,
                                              const float* __restrict__ ld_,
                                              const float* __restrict__ etb,
                                              const float* __restrict__ h,
                                              float* __restrict__ out, int N) {
    int grp = threadIdx.x >> 4;
    int l = threadIdx.x & 15;
    int n = blockIdx.x * 16 + grp;
    if (n >= N) return;
    int s0 = offs[n], s1 = offs[n + 1];
    float myld = ld_[n];

    // pass 1: max (lane-parallel over edges)
    float mx = -FLT_MAX;
    for (int j = s0 + l; j < s1; j += 16) {
        unsigned p = pedge[j];
        float ev = ls[p & 0x0FFFFFFFu] + myld + etb[p >> 28];
        ev = ev > 0.f ? ev : LEAKY * ev;
        mx = fmaxf(mx, ev);
    }
#pragma unroll
    for (int o = 1; o < 16; o <<= 1) mx = fmaxf(mx, __shfl_xor(mx, o, 64));

    // pass 2: group-serial over edges, accumulate sum(w) and sum(w*h)
    const float4* h4 = (const float4*)h;
    float aw_ = 0.f, ax = 0.f, ay = 0.f, az = 0.f, azz = 0.f;
    int j = s0;
    for (; j + 3 < s1; j += 4) {
        unsigned p0 = pedge[j], p1 = pedge[j + 1], p2 = pedge[j + 2], p3 = pedge[j + 3];
        unsigned n0 = p0 & 0x0FFFFFFFu, n1 = p1 & 0x0FFFFFFFu;
        unsigned n2 = p2 & 0x0FFFFFFFu, n3 = p3 & 0x0FFFFFFFu;
        float e0 = ls[n0] + myld + etb[p0 >> 28]; e0 = e0 > 0.f ? e0 : LEAKY * e0;
        float e1 = ls[n1] + myld + etb[p1 >> 28]; e1 = e1 > 0.f ? e1 : LEAKY * e1;
        float e2 = ls[n2] + myld + etb[p2 >> 28]; e2 = e2 > 0.f ? e2 : LEAKY * e2;
        float e3 = ls[n3] + myld + etb[p3 >> 28]; e3 = e3 > 0.f ? e3 : LEAKY * e3;
        float w0 = __expf(e0 - mx), w1 = __expf(e1 - mx);
        float w2 = __expf(e2 - mx), w3 = __expf(e3 - mx);
        float4 v0 = h4[(size_t)n0 * 16 + l];
        float4 v1 = h4[(size_t)n1 * 16 + l];
        float4 v2 = h4[(size_t)n2 * 16 + l];
        float4 v3 = h4[(size_t)n3 * 16 + l];
        aw_ += (w0 + w1) + (w2 + w3);
        ax  += v0.x * w0 + v1.x * w1 + v2.x * w2 + v3.x * w3;
        ay  += v0.y * w0 + v1.y * w1 + v2.y * w2 + v3.y * w3;
        az  += v0.z * w0 + v1.z * w1 + v2.z * w2 + v3.z * w3;
        azz += v0.w * w0 + v1.w * w1 + v2.w * w2 + v3.w * w3;
    }
    for (; j < s1; j++) {
        unsigned p0 = pedge[j];
        unsigned n0 = p0 & 0x0FFFFFFFu;
        float e0 = ls[n0] + myld + etb[p0 >> 28]; e0 = e0 > 0.f ? e0 : LEAKY * e0;
        float w0 = __expf(e0 - mx);
        float4 v0 = h4[(size_t)n0 * 16 + l];
        aw_ += w0;
        ax += v0.x * w0; ay += v0.y * w0; az += v0.z * w0; azz += v0.w * w0;
    }
    float invd = 1.0f / (aw_ + 1e-16f);
    float4 r;
    r.x = fmaxf(ax  * invd, 0.f);
    r.y = fmaxf(ay  * invd, 0.f);
    r.z = fmaxf(az  * invd, 0.f);
    r.w = fmaxf(azz * invd, 0.f);
    ((float4*)out)[(size_t)n * 16 + l] = r;
}

// ---------------- pooling + critic MLP ----------------
__global__ __launch_bounds__(256) void pool_k(const int* __restrict__ batch,
                                              const float* __restrict__ act,
                                              float* __restrict__ gp, int N) {
    __shared__ float s[256];
    int g = blockIdx.x;
    int f = threadIdx.x & 63;
    int rc = threadIdx.x >> 6;
    int lo, hi;
    { int a = 0, b = N; while (a < b) { int m = (a + b) >> 1; if (batch[m] < g) a = m + 1; else b = m; } lo = a; }
    { int a = lo, b = N; while (a < b) { int m = (a + b) >> 1; if (batch[m] < g + 1) a = m + 1; else b = m; } hi = a; }
    float acc = 0.f;
    for (int n = lo + rc; n < hi; n += 4) acc += act[(size_t)n * 64 + f];
    s[threadIdx.x] = acc;
    __syncthreads();
    if (threadIdx.x < 64)
        gp[g * 64 + threadIdx.x] = s[threadIdx.x] + s[threadIdx.x + 64] + s[threadIdx.x + 128] + s[threadIdx.x + 192];
}

__global__ __launch_bounds__(128) void mlp_k(const float* __restrict__ gp,
                                             const float* __restrict__ W0,
                                             const float* __restrict__ b0,
                                             const float* __restrict__ W1,
                                             const float* __restrict__ b1,
                                             const float* __restrict__ fW,
                                             const float* __restrict__ fb,
                                             float* __restrict__ out) {
    __shared__ float gv[64];
    __shared__ float t1[128];
    __shared__ float t2[128];
    __shared__ float part[2];
    int g = blockIdx.x;
    int t = threadIdx.x;
    if (t < 64) gv[t] = gp[g * 64 + t];
    __syncthreads();
    float acc = b0[t];
    for (int k = 0; k < 64; k++) acc += gv[k] * W0[k * 128 + t];
    t1[t] = fmaxf(acc, 0.f);
    __syncthreads();
    acc = b1[t];
    for (int k = 0; k < 128; k++) acc += t1[k] * W1[k * 128 + t];
    t2[t] = fmaxf(acc, 0.f);
    __syncthreads();
    float v = t2[t] * fW[t];
    for (int o = 32; o > 0; o >>= 1) v += __shfl_xor(v, o, 64);
    if ((t & 63) == 0) part[t >> 6] = v;
    __syncthreads();
    if (t == 0) out[g] = part[0] + part[1] + fb[0];
}

extern "C" void kernel_launch(void* const* d_in, const int* in_sizes, int n_in,
                              void* d_out, int out_size, void* d_ws, size_t ws_size,
                              hipStream_t stream) {
    const float* x    = (const float*)d_in[0];
    const int*   src  = (const int*)d_in[1];
    const int*   dst  = (const int*)d_in[2];
    const int*   et   = (const int*)d_in[3];
    const int*   batch= (const int*)d_in[4];
    const float* W0   = (const float*)d_in[6];
    const float* W1   = (const float*)d_in[7];
    const float* W2   = (const float*)d_in[8];
    const float* a_src= (const float*)d_in[9];
    const float* a_dst= (const float*)d_in[10];
    const float* etb  = (const float*)d_in[11];
    const float* eW0  = (const float*)d_in[12];
    const float* eb0  = (const float*)d_in[13];
    const float* eW1  = (const float*)d_in[14];
    const float* eb1  = (const float*)d_in[15];
    const float* fW   = (const float*)d_in[16];
    const float* fb   = (const float*)d_in[17];
    float* out = (float*)d_out;

    const int H = in_sizes[9] / 3;       // 64
    const int F = in_sizes[6] / H;       // 128
    const int N = in_sizes[0] / F;       // 50000
    const int E = in_sizes[1];           // 800000
    const int T = in_sizes[11] / 3;      // 3
    const int G = out_size;              // 512

    float*    hA    = (float*)d_ws;           // N*64
    float*    hB    = hA + (size_t)N * 64;    // N*64
    float*    ls    = hB + (size_t)N * 64;    // N
    float*    ld_   = ls + N;                 // N
    float*    gp    = ld_ + N;                // G*64
    int*      deg   = (int*)(gp + (size_t)G * 64);  // N
    int*      offs  = deg + N;                // N+1
    int*      rank  = offs + N + 1;           // E
    unsigned* pedge = (unsigned*)(rank + E);  // E
    int*      bsum  = (int*)(pedge + E);      // NB

    const int NB = (N + SCAN_B - 1) / SCAN_B;

    hipMemsetAsync(deg, 0, (size_t)N * sizeof(int), stream);

    rank_k<<<(E + 255) / 256, 256, 0, stream>>>(dst, deg, rank, E);
    scan1_k<<<NB, SCAN_B, 0, stream>>>(deg, offs, bsum, N);
    scan2_k<<<1, 1, 0, stream>>>(bsum, offs, NB, N);
    scan3_k<<<NB, SCAN_B, 0, stream>>>(offs, bsum, N);
    scatter_k<<<(E + 255) / 256, 256, 0, stream>>>(src, dst, et, offs, rank, pedge, E);

    const int NB64 = (N + 63) / 64;
    const int NB16 = (N + 15) / 16;

    // ---- layer 0 ----
    gemm_fused_k<128><<<NB64, 256, 0, stream>>>(x, W0, a_src + 0 * H, a_dst + 0 * H, hA, ls, ld_, N);
    attn_k<<<NB16, 256, 0, stream>>>(offs, pedge, ls, ld_, etb + 0 * T, hA, hB, N);

    // ---- layer 1 ----
    gemm_fused_k<64><<<NB64, 256, 0, stream>>>(hB, W1, a_src + 1 * H, a_dst + 1 * H, hA, ls, ld_, N);
    attn_k<<<NB16, 256, 0, stream>>>(offs, pedge, ls, ld_, etb + 1 * T, hA, hB, N);

    // ---- layer 2 ----
    gemm_fused_k<64><<<NB64, 256, 0, stream>>>(hB, W2, a_src + 2 * H, a_dst + 2 * H, hA, ls, ld_, N);
    attn_k<<<NB16, 256, 0, stream>>>(offs, pedge, ls, ld_, etb + 2 * T, hA, hB, N);

    // ---- pool + MLP ----
    pool_k<<<G, 256, 0, stream>>>(batch, hB, gp, N);
    mlp_k<<<G, 128, 0, stream>>>(gp, eW0, eb0, eW1, eb1, fW, fb, out);
}

// Round 6
// 224.392 us; speedup vs baseline: 1.3402x; 1.0927x over previous
//
#include <hip/hip_runtime.h>
#include <hip/hip_bf16.h>
#include <float.h>

#define LEAKY 0.2f
#define SCAN_B 512

__device__ __forceinline__ unsigned short f2bf_rne(float f) {
    unsigned u = __float_as_uint(f);
    unsigned r = (u + 0x7FFFu + ((u >> 16) & 1u)) >> 16;
    return (unsigned short)r;
}
__device__ __forceinline__ float bf2f(unsigned short s) {
    return __uint_as_float((unsigned)s << 16);
}

// ---------------- CSR build ----------------
__global__ void zero_k(int* __restrict__ p, int n) {
    int i = blockIdx.x * blockDim.x + threadIdx.x;
    if (i < n) p[i] = 0;
}

// rank pass: deg histogram AND per-edge rank (coalesced store)
__global__ void rank_k(const int* __restrict__ dst, int* __restrict__ deg,
                       int* __restrict__ rank, int E) {
    int e = blockIdx.x * blockDim.x + threadIdx.x;
    if (e < E) rank[e] = atomicAdd(&deg[dst[e]], 1);
}

__global__ void scan1_k(const int* __restrict__ deg, int* __restrict__ offs,
                        int* __restrict__ bsum, int N) {
    __shared__ int s[SCAN_B];
    int i = blockIdx.x * SCAN_B + threadIdx.x;
    int v = (i < N) ? deg[i] : 0;
    s[threadIdx.x] = v;
    __syncthreads();
    for (int off = 1; off < SCAN_B; off <<= 1) {
        int t = (threadIdx.x >= off) ? s[threadIdx.x - off] : 0;
        __syncthreads();
        s[threadIdx.x] += t;
        __syncthreads();
    }
    if (i < N) offs[i] = s[threadIdx.x] - v;   // exclusive
    if (threadIdx.x == SCAN_B - 1) bsum[blockIdx.x] = s[threadIdx.x];
}

__global__ void scan2_k(int* __restrict__ bsum, int* __restrict__ offs, int NB, int N) {
    if (blockIdx.x == 0 && threadIdx.x == 0) {
        int run = 0;
        for (int b = 0; b < NB; b++) { int t = bsum[b]; bsum[b] = run; run += t; }
        offs[N] = run;
    }
}

__global__ void scan3_k(int* __restrict__ offs, const int* __restrict__ bsum, int N) {
    int i = blockIdx.x * blockDim.x + threadIdx.x;
    if (i < N) offs[i] += bsum[i / SCAN_B];
}

// atomic-free scatter: position = offs[dst] + rank  (offs stays exclusive)
__global__ void scatter_k(const int* __restrict__ src, const int* __restrict__ dst,
                          const int* __restrict__ et, const int* __restrict__ offs,
                          const int* __restrict__ rank, unsigned* __restrict__ pedge, int E) {
    int e = blockIdx.x * blockDim.x + threadIdx.x;
    if (e < E) {
        int j = offs[dst[e]] + rank[e];
        pedge[j] = ((unsigned)et[e] << 28) | (unsigned)src[e];
    }
}

// ---------------- fused GEMM + logits (H = 64 baked in) ----------------
// h output is bf16 (consumed only by attn_k's random gather); logits fp32.
template <int FIN>
__global__ __launch_bounds__(256) void gemm_fused_k(const float* __restrict__ in,
                                                    const float* __restrict__ W,
                                                    const float* __restrict__ a_s,
                                                    const float* __restrict__ a_d,
                                                    unsigned short* __restrict__ h,
                                                    float* __restrict__ ls,
                                                    float* __restrict__ ld_, int N) {
    __shared__ float in_s[64][FIN + 4];
    __shared__ float Wl[FIN][64];

    const int rbase = blockIdx.x * 64;
    const int NV4 = FIN / 4;

    for (int t = threadIdx.x; t < FIN * 16; t += 256) {
        float4 v = *(const float4*)(W + (size_t)t * 4);
        *(float4*)((float*)Wl + (size_t)t * 4) = v;
    }
    for (int t = threadIdx.x; t < 64 * NV4; t += 256) {
        int r = t / NV4, k4 = t % NV4;
        int gr = rbase + r;
        if (gr >= N) gr = N - 1;
        float4 v = *(const float4*)(in + (size_t)gr * FIN + k4 * 4);
        *(float4*)&in_s[r][k4 * 4] = v;
    }
    __syncthreads();

    const int ty = threadIdx.x >> 4;
    const int tx = threadIdx.x & 15;

    float acc[4][4] = {};
#pragma unroll 4
    for (int k = 0; k < FIN; ++k) {
        float4 wv = *(const float4*)&Wl[k][tx * 4];
        float a0 = in_s[ty * 4 + 0][k];
        float a1 = in_s[ty * 4 + 1][k];
        float a2 = in_s[ty * 4 + 2][k];
        float a3 = in_s[ty * 4 + 3][k];
        acc[0][0] += a0 * wv.x; acc[0][1] += a0 * wv.y; acc[0][2] += a0 * wv.z; acc[0][3] += a0 * wv.w;
        acc[1][0] += a1 * wv.x; acc[1][1] += a1 * wv.y; acc[1][2] += a1 * wv.z; acc[1][3] += a1 * wv.w;
        acc[2][0] += a2 * wv.x; acc[2][1] += a2 * wv.y; acc[2][2] += a2 * wv.z; acc[2][3] += a2 * wv.w;
        acc[3][0] += a3 * wv.x; acc[3][1] += a3 * wv.y; acc[3][2] += a3 * wv.z; acc[3][3] += a3 * wv.w;
    }

    float4 asv = *(const float4*)(a_s + tx * 4);
    float4 adv = *(const float4*)(a_d + tx * 4);
#pragma unroll
    for (int i = 0; i < 4; ++i) {
        int row = rbase + ty * 4 + i;
        float lsv = acc[i][0] * asv.x + acc[i][1] * asv.y + acc[i][2] * asv.z + acc[i][3] * asv.w;
        float ldv = acc[i][0] * adv.x + acc[i][1] * adv.y + acc[i][2] * adv.z + acc[i][3] * adv.w;
        for (int o = 1; o < 16; o <<= 1) {
            lsv += __shfl_xor(lsv, o, 64);
            ldv += __shfl_xor(ldv, o, 64);
        }
        if (row < N) {
            ushort4 hv;
            hv.x = f2bf_rne(acc[i][0]);
            hv.y = f2bf_rne(acc[i][1]);
            hv.z = f2bf_rne(acc[i][2]);
            hv.w = f2bf_rne(acc[i][3]);
            ((ushort4*)h)[(size_t)row * 16 + tx] = hv;
            if (tx == 0) { ls[row] = lsv; ld_[row] = ldv; }
        }
    }
}

// ---------------- fused edge softmax + weighted gather (bf16 h rows) ----------------
__global__ __launch_bounds__(256) void attn_k(const int* __restrict__ offs,
                                              const unsigned* __restrict__ pedge,
                                              const float* __restrict__ ls,
                                              const float* __restrict__ ld_,
                                              const float* __restrict__ etb,
                                              const unsigned short* __restrict__ h,
                                              float* __restrict__ out, int N) {
    int grp = threadIdx.x >> 4;
    int l = threadIdx.x & 15;
    int n = blockIdx.x * 16 + grp;
    if (n >= N) return;
    int s0 = offs[n], s1 = offs[n + 1];
    float myld = ld_[n];

    // pass 1: max (lane-parallel over edges)
    float mx = -FLT_MAX;
    for (int j = s0 + l; j < s1; j += 16) {
        unsigned p = pedge[j];
        float ev = ls[p & 0x0FFFFFFFu] + myld + etb[p >> 28];
        ev = ev > 0.f ? ev : LEAKY * ev;
        mx = fmaxf(mx, ev);
    }
#pragma unroll
    for (int o = 1; o < 16; o <<= 1) mx = fmaxf(mx, __shfl_xor(mx, o, 64));

    // pass 2: group-serial over edges, accumulate sum(w) and sum(w*h)
    const ushort4* h4 = (const ushort4*)h;
    float aw_ = 0.f, ax = 0.f, ay = 0.f, az = 0.f, azz = 0.f;
    int j = s0;
    for (; j + 3 < s1; j += 4) {
        unsigned p0 = pedge[j], p1 = pedge[j + 1], p2 = pedge[j + 2], p3 = pedge[j + 3];
        unsigned n0 = p0 & 0x0FFFFFFFu, n1 = p1 & 0x0FFFFFFFu;
        unsigned n2 = p2 & 0x0FFFFFFFu, n3 = p3 & 0x0FFFFFFFu;
        float e0 = ls[n0] + myld + etb[p0 >> 28]; e0 = e0 > 0.f ? e0 : LEAKY * e0;
        float e1 = ls[n1] + myld + etb[p1 >> 28]; e1 = e1 > 0.f ? e1 : LEAKY * e1;
        float e2 = ls[n2] + myld + etb[p2 >> 28]; e2 = e2 > 0.f ? e2 : LEAKY * e2;
        float e3 = ls[n3] + myld + etb[p3 >> 28]; e3 = e3 > 0.f ? e3 : LEAKY * e3;
        float w0 = __expf(e0 - mx), w1 = __expf(e1 - mx);
        float w2 = __expf(e2 - mx), w3 = __expf(e3 - mx);
        ushort4 v0 = h4[(size_t)n0 * 16 + l];
        ushort4 v1 = h4[(size_t)n1 * 16 + l];
        ushort4 v2 = h4[(size_t)n2 * 16 + l];
        ushort4 v3 = h4[(size_t)n3 * 16 + l];
        aw_ += (w0 + w1) + (w2 + w3);
        ax  += bf2f(v0.x) * w0 + bf2f(v1.x) * w1 + bf2f(v2.x) * w2 + bf2f(v3.x) * w3;
        ay  += bf2f(v0.y) * w0 + bf2f(v1.y) * w1 + bf2f(v2.y) * w2 + bf2f(v3.y) * w3;
        az  += bf2f(v0.z) * w0 + bf2f(v1.z) * w1 + bf2f(v2.z) * w2 + bf2f(v3.z) * w3;
        azz += bf2f(v0.w) * w0 + bf2f(v1.w) * w1 + bf2f(v2.w) * w2 + bf2f(v3.w) * w3;
    }
    for (; j < s1; j++) {
        unsigned p0 = pedge[j];
        unsigned n0 = p0 & 0x0FFFFFFFu;
        float e0 = ls[n0] + myld + etb[p0 >> 28]; e0 = e0 > 0.f ? e0 : LEAKY * e0;
        float w0 = __expf(e0 - mx);
        ushort4 v0 = h4[(size_t)n0 * 16 + l];
        aw_ += w0;
        ax += bf2f(v0.x) * w0; ay += bf2f(v0.y) * w0;
        az += bf2f(v0.z) * w0; azz += bf2f(v0.w) * w0;
    }
    float invd = 1.0f / (aw_ + 1e-16f);
    float4 r;
    r.x = fmaxf(ax  * invd, 0.f);
    r.y = fmaxf(ay  * invd, 0.f);
    r.z = fmaxf(az  * invd, 0.f);
    r.w = fmaxf(azz * invd, 0.f);
    ((float4*)out)[(size_t)n * 16 + l] = r;
}

// ---------------- pooling + critic MLP ----------------
__global__ __launch_bounds__(256) void pool_k(const int* __restrict__ batch,
                                              const float* __restrict__ act,
                                              float* __restrict__ gp, int N) {
    __shared__ float s[256];
    int g = blockIdx.x;
    int f = threadIdx.x & 63;
    int rc = threadIdx.x >> 6;
    int lo, hi;
    { int a = 0, b = N; while (a < b) { int m = (a + b) >> 1; if (batch[m] < g) a = m + 1; else b = m; } lo = a; }
    { int a = lo, b = N; while (a < b) { int m = (a + b) >> 1; if (batch[m] < g + 1) a = m + 1; else b = m; } hi = a; }
    float acc = 0.f;
    for (int n = lo + rc; n < hi; n += 4) acc += act[(size_t)n * 64 + f];
    s[threadIdx.x] = acc;
    __syncthreads();
    if (threadIdx.x < 64)
        gp[g * 64 + threadIdx.x] = s[threadIdx.x] + s[threadIdx.x + 64] + s[threadIdx.x + 128] + s[threadIdx.x + 192];
}

__global__ __launch_bounds__(128) void mlp_k(const float* __restrict__ gp,
                                             const float* __restrict__ W0,
                                             const float* __restrict__ b0,
                                             const float* __restrict__ W1,
                                             const float* __restrict__ b1,
                                             const float* __restrict__ fW,
                                             const float* __restrict__ fb,
                                             float* __restrict__ out) {
    __shared__ float gv[64];
    __shared__ float t1[128];
    __shared__ float t2[128];
    __shared__ float part[2];
    int g = blockIdx.x;
    int t = threadIdx.x;
    if (t < 64) gv[t] = gp[g * 64 + t];
    __syncthreads();
    float acc = b0[t];
    for (int k = 0; k < 64; k++) acc += gv[k] * W0[k * 128 + t];
    t1[t] = fmaxf(acc, 0.f);
    __syncthreads();
    acc = b1[t];
    for (int k = 0; k < 128; k++) acc += t1[k] * W1[k * 128 + t];
    t2[t] = fmaxf(acc, 0.f);
    __syncthreads();
    float v = t2[t] * fW[t];
    for (int o = 32; o > 0; o >>= 1) v += __shfl_xor(v, o, 64);
    if ((t & 63) == 0) part[t >> 6] = v;
    __syncthreads();
    if (t == 0) out[g] = part[0] + part[1] + fb[0];
}

extern "C" void kernel_launch(void* const* d_in, const int* in_sizes, int n_in,
                              void* d_out, int out_size, void* d_ws, size_t ws_size,
                              hipStream_t stream) {
    const float* x    = (const float*)d_in[0];
    const int*   src  = (const int*)d_in[1];
    const int*   dst  = (const int*)d_in[2];
    const int*   et   = (const int*)d_in[3];
    const int*   batch= (const int*)d_in[4];
    const float* W0   = (const float*)d_in[6];
    const float* W1   = (const float*)d_in[7];
    const float* W2   = (const float*)d_in[8];
    const float* a_src= (const float*)d_in[9];
    const float* a_dst= (const float*)d_in[10];
    const float* etb  = (const float*)d_in[11];
    const float* eW0  = (const float*)d_in[12];
    const float* eb0  = (const float*)d_in[13];
    const float* eW1  = (const float*)d_in[14];
    const float* eb1  = (const float*)d_in[15];
    const float* fW   = (const float*)d_in[16];
    const float* fb   = (const float*)d_in[17];
    float* out = (float*)d_out;

    const int H = in_sizes[9] / 3;       // 64
    const int F = in_sizes[6] / H;       // 128
    const int N = in_sizes[0] / F;       // 50000
    const int E = in_sizes[1];           // 800000
    const int T = in_sizes[11] / 3;      // 3
    const int G = out_size;              // 512

    unsigned short* hA = (unsigned short*)d_ws;                 // N*64 bf16
    float*    hB    = (float*)(hA + (size_t)N * 64);            // N*64 fp32
    float*    ls    = hB + (size_t)N * 64;                      // N
    float*    ld_   = ls + N;                                   // N
    float*    gp    = ld_ + N;                                  // G*64
    int*      deg   = (int*)(gp + (size_t)G * 64);              // N
    int*      offs  = deg + N;                                  // N+1
    int*      rank  = offs + N + 1;                             // E
    unsigned* pedge = (unsigned*)(rank + E);                    // E
    int*      bsum  = (int*)(pedge + E);                        // NB

    const int NB = (N + SCAN_B - 1) / SCAN_B;

    zero_k<<<(N + 255) / 256, 256, 0, stream>>>(deg, N);
    rank_k<<<(E + 255) / 256, 256, 0, stream>>>(dst, deg, rank, E);
    scan1_k<<<NB, SCAN_B, 0, stream>>>(deg, offs, bsum, N);
    scan2_k<<<1, 1, 0, stream>>>(bsum, offs, NB, N);
    scan3_k<<<NB, SCAN_B, 0, stream>>>(offs, bsum, N);
    scatter_k<<<(E + 255) / 256, 256, 0, stream>>>(src, dst, et, offs, rank, pedge, E);

    const int NB64 = (N + 63) / 64;
    const int NB16 = (N + 15) / 16;

    // ---- layer 0 ----
    gemm_fused_k<128><<<NB64, 256, 0, stream>>>(x, W0, a_src + 0 * H, a_dst + 0 * H, hA, ls, ld_, N);
    attn_k<<<NB16, 256, 0, stream>>>(offs, pedge, ls, ld_, etb + 0 * T, hA, hB, N);

    // ---- layer 1 ----
    gemm_fused_k<64><<<NB64, 256, 0, stream>>>(hB, W1, a_src + 1 * H, a_dst + 1 * H, hA, ls, ld_, N);
    attn_k<<<NB16, 256, 0, stream>>>(offs, pedge, ls, ld_, etb + 1 * T, hA, hB, N);

    // ---- layer 2 ----
    gemm_fused_k<64><<<NB64, 256, 0, stream>>>(hB, W2, a_src + 2 * H, a_dst + 2 * H, hA, ls, ld_, N);
    attn_k<<<NB16, 256, 0, stream>>>(offs, pedge, ls, ld_, etb + 2 * T, hA, hB, N);

    // ---- pool + MLP ----
    pool_k<<<G, 256, 0, stream>>>(batch, hB, gp, N);
    mlp_k<<<G, 128, 0, stream>>>(gp, eW0, eb0, eW1, eb1, fW, fb, out);
}

// Round 7
// 198.862 us; speedup vs baseline: 1.5123x; 1.1284x over previous
//
#include <hip/hip_runtime.h>
#include <hip/hip_bf16.h>
#include <float.h>

#define LEAKY 0.2f
#define SCAN_B 512

__device__ __forceinline__ unsigned short f2bf_rne(float f) {
    unsigned u = __float_as_uint(f);
    unsigned r = (u + 0x7FFFu + ((u >> 16) & 1u)) >> 16;
    return (unsigned short)r;
}
__device__ __forceinline__ float bflo(unsigned u) { return __uint_as_float(u << 16); }
__device__ __forceinline__ float bfhi(unsigned u) { return __uint_as_float(u & 0xFFFF0000u); }

// ---------------- CSR build ----------------
__global__ void zero_k(int* __restrict__ p, int n) {
    int i = blockIdx.x * blockDim.x + threadIdx.x;
    if (i < n) p[i] = 0;
}

__global__ void rank_k(const int* __restrict__ dst, int* __restrict__ deg,
                       int* __restrict__ rank, int E) {
    int e = blockIdx.x * blockDim.x + threadIdx.x;
    if (e < E) rank[e] = atomicAdd(&deg[dst[e]], 1);
}

__global__ void scan1_k(const int* __restrict__ deg, int* __restrict__ offs,
                        int* __restrict__ bsum, int N) {
    __shared__ int s[SCAN_B];
    int i = blockIdx.x * SCAN_B + threadIdx.x;
    int v = (i < N) ? deg[i] : 0;
    s[threadIdx.x] = v;
    __syncthreads();
    for (int off = 1; off < SCAN_B; off <<= 1) {
        int t = (threadIdx.x >= off) ? s[threadIdx.x - off] : 0;
        __syncthreads();
        s[threadIdx.x] += t;
        __syncthreads();
    }
    if (i < N) offs[i] = s[threadIdx.x] - v;   // exclusive
    if (threadIdx.x == SCAN_B - 1) bsum[blockIdx.x] = s[threadIdx.x];
}

// single-wave shuffle scan over block sums (NB ~ 98)
__global__ void scan2_k(int* __restrict__ bsum, int* __restrict__ offs, int NB, int N) {
    int lane = threadIdx.x;   // 64 threads
    int carry = 0;
    for (int base = 0; base < NB; base += 64) {
        int i = base + lane;
        int v = (i < NB) ? bsum[i] : 0;
        int s = v;
        for (int o = 1; o < 64; o <<= 1) {
            int t = __shfl_up(s, o, 64);
            if (lane >= o) s += t;
        }
        if (i < NB) bsum[i] = s - v + carry;
        carry += __shfl(s, 63, 64);
    }
    if (lane == 0) offs[N] = carry;
}

__global__ void scan3_k(int* __restrict__ offs, const int* __restrict__ bsum, int N) {
    int i = blockIdx.x * blockDim.x + threadIdx.x;
    if (i < N) offs[i] += bsum[i / SCAN_B];
}

__global__ void scatter_k(const int* __restrict__ src, const int* __restrict__ dst,
                          const int* __restrict__ et, const int* __restrict__ offs,
                          const int* __restrict__ rank, unsigned* __restrict__ pedge, int E) {
    int e = blockIdx.x * blockDim.x + threadIdx.x;
    if (e < E) {
        int j = offs[dst[e]] + rank[e];
        pedge[j] = ((unsigned)et[e] << 28) | (unsigned)src[e];
    }
}

// ---------------- layer-0 GEMM + logits (global input) ----------------
template <int FIN>
__global__ __launch_bounds__(256) void gemm_fused_k(const float* __restrict__ in,
                                                    const float* __restrict__ W,
                                                    const float* __restrict__ a_s,
                                                    const float* __restrict__ a_d,
                                                    unsigned short* __restrict__ h,
                                                    float* __restrict__ ls,
                                                    float* __restrict__ ld_, int N) {
    __shared__ float in_s[64][FIN + 4];
    __shared__ float Wl[FIN][64];

    const int rbase = blockIdx.x * 64;
    const int NV4 = FIN / 4;

    for (int t = threadIdx.x; t < FIN * 16; t += 256) {
        float4 v = *(const float4*)(W + (size_t)t * 4);
        *(float4*)((float*)Wl + (size_t)t * 4) = v;
    }
    for (int t = threadIdx.x; t < 64 * NV4; t += 256) {
        int r = t / NV4, k4 = t % NV4;
        int gr = rbase + r;
        if (gr >= N) gr = N - 1;
        float4 v = *(const float4*)(in + (size_t)gr * FIN + k4 * 4);
        *(float4*)&in_s[r][k4 * 4] = v;
    }
    __syncthreads();

    const int ty = threadIdx.x >> 4;
    const int tx = threadIdx.x & 15;

    float acc[4][4] = {};
#pragma unroll 4
    for (int k = 0; k < FIN; ++k) {
        float4 wv = *(const float4*)&Wl[k][tx * 4];
        float a0 = in_s[ty * 4 + 0][k];
        float a1 = in_s[ty * 4 + 1][k];
        float a2 = in_s[ty * 4 + 2][k];
        float a3 = in_s[ty * 4 + 3][k];
        acc[0][0] += a0 * wv.x; acc[0][1] += a0 * wv.y; acc[0][2] += a0 * wv.z; acc[0][3] += a0 * wv.w;
        acc[1][0] += a1 * wv.x; acc[1][1] += a1 * wv.y; acc[1][2] += a1 * wv.z; acc[1][3] += a1 * wv.w;
        acc[2][0] += a2 * wv.x; acc[2][1] += a2 * wv.y; acc[2][2] += a2 * wv.z; acc[2][3] += a2 * wv.w;
        acc[3][0] += a3 * wv.x; acc[3][1] += a3 * wv.y; acc[3][2] += a3 * wv.z; acc[3][3] += a3 * wv.w;
    }

    float4 asv = *(const float4*)(a_s + tx * 4);
    float4 adv = *(const float4*)(a_d + tx * 4);
#pragma unroll
    for (int i = 0; i < 4; ++i) {
        int row = rbase + ty * 4 + i;
        float lsv = acc[i][0] * asv.x + acc[i][1] * asv.y + acc[i][2] * asv.z + acc[i][3] * asv.w;
        float ldv = acc[i][0] * adv.x + acc[i][1] * adv.y + acc[i][2] * adv.z + acc[i][3] * adv.w;
        for (int o = 1; o < 16; o <<= 1) {
            lsv += __shfl_xor(lsv, o, 64);
            ldv += __shfl_xor(ldv, o, 64);
        }
        if (row < N) {
            ushort4 hv;
            hv.x = f2bf_rne(acc[i][0]);
            hv.y = f2bf_rne(acc[i][1]);
            hv.z = f2bf_rne(acc[i][2]);
            hv.w = f2bf_rne(acc[i][3]);
            ((ushort4*)h)[(size_t)row * 16 + tx] = hv;
            if (tx == 0) { ls[row] = lsv; ld_[row] = ldv; }
        }
    }
}

// ---------------- fused attn (8-lane groups) + GEMM + logits ----------------
// Block handles 64 nodes: attn -> LDS act -> gemm(act*W) -> bf16 h_out + logits.
__global__ __launch_bounds__(256) void attn_gemm_k(const int* __restrict__ offs,
                                                   const unsigned* __restrict__ pedge,
                                                   const float* __restrict__ ls_in,
                                                   const float* __restrict__ ld_in,
                                                   const float* __restrict__ etb,
                                                   const unsigned short* __restrict__ h_in,
                                                   const float* __restrict__ W,
                                                   const float* __restrict__ a_s,
                                                   const float* __restrict__ a_d,
                                                   unsigned short* __restrict__ h_out,
                                                   float* __restrict__ ls_out,
                                                   float* __restrict__ ld_out, int N) {
    __shared__ float Wl[64][64];
    __shared__ float act[64][68];

    const int rbase = blockIdx.x * 64;

    for (int t = threadIdx.x; t < 64 * 16; t += 256)
        *(float4*)((float*)Wl + (size_t)t * 4) = *(const float4*)(W + (size_t)t * 4);

    // ---- attn phase: 8-lane groups, 32 nodes per pass, 2 passes ----
    const int grp = threadIdx.x >> 3;
    const int l = threadIdx.x & 7;
    const uint4* h4 = (const uint4*)h_in;   // 8 bf16 per lane

    for (int p = 0; p < 2; ++p) {
        int r = p * 32 + grp;
        int n = rbase + r;
        float acc[8] = {};
        float aw_ = 0.f;
        if (n < N) {
            int s0 = offs[n], s1 = offs[n + 1];
            float myld = ld_in[n];
            float mx = -FLT_MAX;
            for (int j = s0 + l; j < s1; j += 8) {
                unsigned pp = pedge[j];
                float ev = ls_in[pp & 0x0FFFFFFFu] + myld + etb[pp >> 28];
                ev = ev > 0.f ? ev : LEAKY * ev;
                mx = fmaxf(mx, ev);
            }
#pragma unroll
            for (int o = 1; o < 8; o <<= 1) mx = fmaxf(mx, __shfl_xor(mx, o, 64));

            int j = s0;
            for (; j + 3 < s1; j += 4) {
                unsigned p0 = pedge[j], p1 = pedge[j + 1], p2 = pedge[j + 2], p3 = pedge[j + 3];
                unsigned n0 = p0 & 0x0FFFFFFFu, n1 = p1 & 0x0FFFFFFFu;
                unsigned n2 = p2 & 0x0FFFFFFFu, n3 = p3 & 0x0FFFFFFFu;
                float e0 = ls_in[n0] + myld + etb[p0 >> 28]; e0 = e0 > 0.f ? e0 : LEAKY * e0;
                float e1 = ls_in[n1] + myld + etb[p1 >> 28]; e1 = e1 > 0.f ? e1 : LEAKY * e1;
                float e2 = ls_in[n2] + myld + etb[p2 >> 28]; e2 = e2 > 0.f ? e2 : LEAKY * e2;
                float e3 = ls_in[n3] + myld + etb[p3 >> 28]; e3 = e3 > 0.f ? e3 : LEAKY * e3;
                float w0 = __expf(e0 - mx), w1 = __expf(e1 - mx);
                float w2 = __expf(e2 - mx), w3 = __expf(e3 - mx);
                uint4 v0 = h4[(size_t)n0 * 8 + l];
                uint4 v1 = h4[(size_t)n1 * 8 + l];
                uint4 v2 = h4[(size_t)n2 * 8 + l];
                uint4 v3 = h4[(size_t)n3 * 8 + l];
                aw_ += (w0 + w1) + (w2 + w3);
                acc[0] += bflo(v0.x) * w0 + bflo(v1.x) * w1 + bflo(v2.x) * w2 + bflo(v3.x) * w3;
                acc[1] += bfhi(v0.x) * w0 + bfhi(v1.x) * w1 + bfhi(v2.x) * w2 + bfhi(v3.x) * w3;
                acc[2] += bflo(v0.y) * w0 + bflo(v1.y) * w1 + bflo(v2.y) * w2 + bflo(v3.y) * w3;
                acc[3] += bfhi(v0.y) * w0 + bfhi(v1.y) * w1 + bfhi(v2.y) * w2 + bfhi(v3.y) * w3;
                acc[4] += bflo(v0.z) * w0 + bflo(v1.z) * w1 + bflo(v2.z) * w2 + bflo(v3.z) * w3;
                acc[5] += bfhi(v0.z) * w0 + bfhi(v1.z) * w1 + bfhi(v2.z) * w2 + bfhi(v3.z) * w3;
                acc[6] += bflo(v0.w) * w0 + bflo(v1.w) * w1 + bflo(v2.w) * w2 + bflo(v3.w) * w3;
                acc[7] += bfhi(v0.w) * w0 + bfhi(v1.w) * w1 + bfhi(v2.w) * w2 + bfhi(v3.w) * w3;
            }
            for (; j < s1; j++) {
                unsigned p0 = pedge[j];
                unsigned n0 = p0 & 0x0FFFFFFFu;
                float e0 = ls_in[n0] + myld + etb[p0 >> 28]; e0 = e0 > 0.f ? e0 : LEAKY * e0;
                float w0 = __expf(e0 - mx);
                uint4 v0 = h4[(size_t)n0 * 8 + l];
                aw_ += w0;
                acc[0] += bflo(v0.x) * w0; acc[1] += bfhi(v0.x) * w0;
                acc[2] += bflo(v0.y) * w0; acc[3] += bfhi(v0.y) * w0;
                acc[4] += bflo(v0.z) * w0; acc[5] += bfhi(v0.z) * w0;
                acc[6] += bflo(v0.w) * w0; acc[7] += bfhi(v0.w) * w0;
            }
        }
        float invd = 1.0f / (aw_ + 1e-16f);
        float4 o0, o1;
        o0.x = fmaxf(acc[0] * invd, 0.f); o0.y = fmaxf(acc[1] * invd, 0.f);
        o0.z = fmaxf(acc[2] * invd, 0.f); o0.w = fmaxf(acc[3] * invd, 0.f);
        o1.x = fmaxf(acc[4] * invd, 0.f); o1.y = fmaxf(acc[5] * invd, 0.f);
        o1.z = fmaxf(acc[6] * invd, 0.f); o1.w = fmaxf(acc[7] * invd, 0.f);
        if (n >= N) { o0 = make_float4(0, 0, 0, 0); o1 = o0; }
        *(float4*)&act[r][l * 8] = o0;
        *(float4*)&act[r][l * 8 + 4] = o1;
    }
    __syncthreads();

    // ---- gemm phase: act (LDS) x W -> h_out, logits ----
    const int ty = threadIdx.x >> 4;
    const int tx = threadIdx.x & 15;

    float acc[4][4] = {};
#pragma unroll 4
    for (int k = 0; k < 64; ++k) {
        float4 wv = *(const float4*)&Wl[k][tx * 4];
        float a0 = act[ty * 4 + 0][k];
        float a1 = act[ty * 4 + 1][k];
        float a2 = act[ty * 4 + 2][k];
        float a3 = act[ty * 4 + 3][k];
        acc[0][0] += a0 * wv.x; acc[0][1] += a0 * wv.y; acc[0][2] += a0 * wv.z; acc[0][3] += a0 * wv.w;
        acc[1][0] += a1 * wv.x; acc[1][1] += a1 * wv.y; acc[1][2] += a1 * wv.z; acc[1][3] += a1 * wv.w;
        acc[2][0] += a2 * wv.x; acc[2][1] += a2 * wv.y; acc[2][2] += a2 * wv.z; acc[2][3] += a2 * wv.w;
        acc[3][0] += a3 * wv.x; acc[3][1] += a3 * wv.y; acc[3][2] += a3 * wv.z; acc[3][3] += a3 * wv.w;
    }

    float4 asv = *(const float4*)(a_s + tx * 4);
    float4 adv = *(const float4*)(a_d + tx * 4);
#pragma unroll
    for (int i = 0; i < 4; ++i) {
        int row = rbase + ty * 4 + i;
        float lsv = acc[i][0] * asv.x + acc[i][1] * asv.y + acc[i][2] * asv.z + acc[i][3] * asv.w;
        float ldv = acc[i][0] * adv.x + acc[i][1] * adv.y + acc[i][2] * adv.z + acc[i][3] * adv.w;
        for (int o = 1; o < 16; o <<= 1) {
            lsv += __shfl_xor(lsv, o, 64);
            ldv += __shfl_xor(ldv, o, 64);
        }
        if (row < N) {
            ushort4 hv;
            hv.x = f2bf_rne(acc[i][0]);
            hv.y = f2bf_rne(acc[i][1]);
            hv.z = f2bf_rne(acc[i][2]);
            hv.w = f2bf_rne(acc[i][3]);
            ((ushort4*)h_out)[(size_t)row * 16 + tx] = hv;
            if (tx == 0) { ls_out[row] = lsv; ld_out[row] = ldv; }
        }
    }
}

// ---------------- final attn (8-lane groups, fp32 output) ----------------
__global__ __launch_bounds__(256) void attn_final_k(const int* __restrict__ offs,
                                                    const unsigned* __restrict__ pedge,
                                                    const float* __restrict__ ls_in,
                                                    const float* __restrict__ ld_in,
                                                    const float* __restrict__ etb,
                                                    const unsigned short* __restrict__ h_in,
                                                    float* __restrict__ out, int N) {
    const int grp = threadIdx.x >> 3;
    const int l = threadIdx.x & 7;
    int n = blockIdx.x * 32 + grp;
    if (n >= N) return;
    int s0 = offs[n], s1 = offs[n + 1];
    float myld = ld_in[n];
    const uint4* h4 = (const uint4*)h_in;

    float mx = -FLT_MAX;
    for (int j = s0 + l; j < s1; j += 8) {
        unsigned pp = pedge[j];
        float ev = ls_in[pp & 0x0FFFFFFFu] + myld + etb[pp >> 28];
        ev = ev > 0.f ? ev : LEAKY * ev;
        mx = fmaxf(mx, ev);
    }
#pragma unroll
    for (int o = 1; o < 8; o <<= 1) mx = fmaxf(mx, __shfl_xor(mx, o, 64));

    float acc[8] = {};
    float aw_ = 0.f;
    int j = s0;
    for (; j + 3 < s1; j += 4) {
        unsigned p0 = pedge[j], p1 = pedge[j + 1], p2 = pedge[j + 2], p3 = pedge[j + 3];
        unsigned n0 = p0 & 0x0FFFFFFFu, n1 = p1 & 0x0FFFFFFFu;
        unsigned n2 = p2 & 0x0FFFFFFFu, n3 = p3 & 0x0FFFFFFFu;
        float e0 = ls_in[n0] + myld + etb[p0 >> 28]; e0 = e0 > 0.f ? e0 : LEAKY * e0;
        float e1 = ls_in[n1] + myld + etb[p1 >> 28]; e1 = e1 > 0.f ? e1 : LEAKY * e1;
        float e2 = ls_in[n2] + myld + etb[p2 >> 28]; e2 = e2 > 0.f ? e2 : LEAKY * e2;
        float e3 = ls_in[n3] + myld + etb[p3 >> 28]; e3 = e3 > 0.f ? e3 : LEAKY * e3;
        float w0 = __expf(e0 - mx), w1 = __expf(e1 - mx);
        float w2 = __expf(e2 - mx), w3 = __expf(e3 - mx);
        uint4 v0 = h4[(size_t)n0 * 8 + l];
        uint4 v1 = h4[(size_t)n1 * 8 + l];
        uint4 v2 = h4[(size_t)n2 * 8 + l];
        uint4 v3 = h4[(size_t)n3 * 8 + l];
        aw_ += (w0 + w1) + (w2 + w3);
        acc[0] += bflo(v0.x) * w0 + bflo(v1.x) * w1 + bflo(v2.x) * w2 + bflo(v3.x) * w3;
        acc[1] += bfhi(v0.x) * w0 + bfhi(v1.x) * w1 + bfhi(v2.x) * w2 + bfhi(v3.x) * w3;
        acc[2] += bflo(v0.y) * w0 + bflo(v1.y) * w1 + bflo(v2.y) * w2 + bflo(v3.y) * w3;
        acc[3] += bfhi(v0.y) * w0 + bfhi(v1.y) * w1 + bfhi(v2.y) * w2 + bfhi(v3.y) * w3;
        acc[4] += bflo(v0.z) * w0 + bflo(v1.z) * w1 + bflo(v2.z) * w2 + bflo(v3.z) * w3;
        acc[5] += bfhi(v0.z) * w0 + bfhi(v1.z) * w1 + bfhi(v2.z) * w2 + bfhi(v3.z) * w3;
        acc[6] += bflo(v0.w) * w0 + bflo(v1.w) * w1 + bflo(v2.w) * w2 + bflo(v3.w) * w3;
        acc[7] += bfhi(v0.w) * w0 + bfhi(v1.w) * w1 + bfhi(v2.w) * w2 + bfhi(v3.w) * w3;
    }
    for (; j < s1; j++) {
        unsigned p0 = pedge[j];
        unsigned n0 = p0 & 0x0FFFFFFFu;
        float e0 = ls_in[n0] + myld + etb[p0 >> 28]; e0 = e0 > 0.f ? e0 : LEAKY * e0;
        float w0 = __expf(e0 - mx);
        uint4 v0 = h4[(size_t)n0 * 8 + l];
        aw_ += w0;
        acc[0] += bflo(v0.x) * w0; acc[1] += bfhi(v0.x) * w0;
        acc[2] += bflo(v0.y) * w0; acc[3] += bfhi(v0.y) * w0;
        acc[4] += bflo(v0.z) * w0; acc[5] += bfhi(v0.z) * w0;
        acc[6] += bflo(v0.w) * w0; acc[7] += bfhi(v0.w) * w0;
    }
    float invd = 1.0f / (aw_ + 1e-16f);
    float4 o0, o1;
    o0.x = fmaxf(acc[0] * invd, 0.f); o0.y = fmaxf(acc[1] * invd, 0.f);
    o0.z = fmaxf(acc[2] * invd, 0.f); o0.w = fmaxf(acc[3] * invd, 0.f);
    o1.x = fmaxf(acc[4] * invd, 0.f); o1.y = fmaxf(acc[5] * invd, 0.f);
    o1.z = fmaxf(acc[6] * invd, 0.f); o1.w = fmaxf(acc[7] * invd, 0.f);
    *(float4*)&out[(size_t)n * 64 + l * 8] = o0;
    *(float4*)&out[(size_t)n * 64 + l * 8 + 4] = o1;
}

// ---------------- fused pool + critic MLP ----------------
__global__ __launch_bounds__(128) void poolmlp_k(const int* __restrict__ batch,
                                                 const float* __restrict__ act,
                                                 const float* __restrict__ W0,
                                                 const float* __restrict__ b0,
                                                 const float* __restrict__ W1,
                                                 const float* __restrict__ b1,
                                                 const float* __restrict__ fW,
                                                 const float* __restrict__ fb,
                                                 float* __restrict__ out, int N) {
    __shared__ float s[128];
    __shared__ float gv[64];
    __shared__ float t1[128];
    __shared__ float t2[128];
    __shared__ float part[2];
    int g = blockIdx.x;
    int t = threadIdx.x;
    int f = t & 63;
    int rc = t >> 6;   // 0..1
    int lo, hi;
    { int a = 0, b = N; while (a < b) { int m = (a + b) >> 1; if (batch[m] < g) a = m + 1; else b = m; } lo = a; }
    { int a = lo, b = N; while (a < b) { int m = (a + b) >> 1; if (batch[m] < g + 1) a = m + 1; else b = m; } hi = a; }
    float acc = 0.f;
    for (int n = lo + rc; n < hi; n += 2) acc += act[(size_t)n * 64 + f];
    s[t] = acc;
    __syncthreads();
    if (t < 64) gv[t] = s[t] + s[t + 64];
    __syncthreads();
    acc = b0[t];
    for (int k = 0; k < 64; k++) acc += gv[k] * W0[k * 128 + t];
    t1[t] = fmaxf(acc, 0.f);
    __syncthreads();
    acc = b1[t];
    for (int k = 0; k < 128; k++) acc += t1[k] * W1[k * 128 + t];
    t2[t] = fmaxf(acc, 0.f);
    __syncthreads();
    float v = t2[t] * fW[t];
    for (int o = 32; o > 0; o >>= 1) v += __shfl_xor(v, o, 64);
    if ((t & 63) == 0) part[t >> 6] = v;
    __syncthreads();
    if (t == 0) out[g] = part[0] + part[1] + fb[0];
}

extern "C" void kernel_launch(void* const* d_in, const int* in_sizes, int n_in,
                              void* d_out, int out_size, void* d_ws, size_t ws_size,
                              hipStream_t stream) {
    const float* x    = (const float*)d_in[0];
    const int*   src  = (const int*)d_in[1];
    const int*   dst  = (const int*)d_in[2];
    const int*   et   = (const int*)d_in[3];
    const int*   batch= (const int*)d_in[4];
    const float* W0   = (const float*)d_in[6];
    const float* W1   = (const float*)d_in[7];
    const float* W2   = (const float*)d_in[8];
    const float* a_src= (const float*)d_in[9];
    const float* a_dst= (const float*)d_in[10];
    const float* etb  = (const float*)d_in[11];
    const float* eW0  = (const float*)d_in[12];
    const float* eb0  = (const float*)d_in[13];
    const float* eW1  = (const float*)d_in[14];
    const float* eb1  = (const float*)d_in[15];
    const float* fW   = (const float*)d_in[16];
    const float* fb   = (const float*)d_in[17];
    float* out = (float*)d_out;

    const int H = in_sizes[9] / 3;       // 64
    const int F = in_sizes[6] / H;       // 128
    const int N = in_sizes[0] / F;       // 50000
    const int E = in_sizes[1];           // 800000
    const int T = in_sizes[11] / 3;      // 3
    const int G = out_size;              // 512

    unsigned short* hA = (unsigned short*)d_ws;                 // N*64 bf16
    unsigned short* hC = hA + (size_t)N * 64;                   // N*64 bf16
    float*    hB    = (float*)(hC + (size_t)N * 64);            // N*64 fp32
    float*    ls0   = hB + (size_t)N * 64;                      // N
    float*    ld0   = ls0 + N;                                  // N
    float*    ls1   = ld0 + N;                                  // N
    float*    ld1   = ls1 + N;                                  // N
    int*      deg   = (int*)(ld1 + N);                          // N
    int*      offs  = deg + N;                                  // N+1
    int*      rank  = offs + N + 1;                             // E
    unsigned* pedge = (unsigned*)(rank + E);                    // E
    int*      bsum  = (int*)(pedge + E);                        // NB

    const int NB = (N + SCAN_B - 1) / SCAN_B;

    zero_k<<<(N + 255) / 256, 256, 0, stream>>>(deg, N);
    rank_k<<<(E + 255) / 256, 256, 0, stream>>>(dst, deg, rank, E);
    scan1_k<<<NB, SCAN_B, 0, stream>>>(deg, offs, bsum, N);
    scan2_k<<<1, 64, 0, stream>>>(bsum, offs, NB, N);
    scan3_k<<<NB, SCAN_B, 0, stream>>>(offs, bsum, N);
    scatter_k<<<(E + 255) / 256, 256, 0, stream>>>(src, dst, et, offs, rank, pedge, E);

    const int NB64 = (N + 63) / 64;
    const int NB32 = (N + 31) / 32;

    // layer 0: x -> h0 (hA), logits0
    gemm_fused_k<128><<<NB64, 256, 0, stream>>>(x, W0, a_src + 0 * H, a_dst + 0 * H, hA, ls0, ld0, N);
    // layer 1: attn(h0) -> gemm W1 -> h1 (hC), logits1
    attn_gemm_k<<<NB64, 256, 0, stream>>>(offs, pedge, ls0, ld0, etb + 0 * T, hA,
                                          W1, a_src + 1 * H, a_dst + 1 * H, hC, ls1, ld1, N);
    // layer 2: attn(h1) -> gemm W2 -> h2 (hA), logits2
    attn_gemm_k<<<NB64, 256, 0, stream>>>(offs, pedge, ls1, ld1, etb + 1 * T, hC,
                                          W2, a_src + 2 * H, a_dst + 2 * H, hA, ls0, ld0, N);
    // final attn: attn(h2) -> hB (fp32)
    attn_final_k<<<NB32, 256, 0, stream>>>(offs, pedge, ls0, ld0, etb + 2 * T, hA, hB, N);

    // pool + MLP
    poolmlp_k<<<G, 128, 0, stream>>>(batch, hB, eW0, eb0, eW1, eb1, fW, fb, out, N);
}